// Round 12
// baseline (316.960 us; speedup 1.0000x reference)
//
#include <hip/hip_runtime.h>

typedef int i32x4 __attribute__((ext_vector_type(4)));

#define AS1 __attribute__((address_space(1)))
#define AS3 __attribute__((address_space(3)))

#define M_DIM 8192
#define N_DIM 8192
#define K_DIM 2048
#define NT 32   // K-tiles of 64 bytes

// ---------------- quantize x: per-tensor scale, 16 elems/thread ----------------
__global__ __launch_bounds__(256) void quant_x_kernel(
    const float* __restrict__ x, const float* __restrict__ in_scale,
    i32x4* __restrict__ qx, int n16)
{
    int idx = blockIdx.x * 256 + threadIdx.x;
    if (idx >= n16) return;
    float s = in_scale[0];
    const float4* xp = reinterpret_cast<const float4*>(x) + (size_t)idx * 4;
    union { char c[16]; i32x4 v; } u;
#pragma unroll
    for (int v4 = 0; v4 < 4; ++v4) {
        float4 f = xp[v4];
        u.c[v4*4+0] = (char)(int)fminf(fmaxf(rintf(f.x / s), -128.f), 127.f);
        u.c[v4*4+1] = (char)(int)fminf(fmaxf(rintf(f.y / s), -128.f), 127.f);
        u.c[v4*4+2] = (char)(int)fminf(fmaxf(rintf(f.z / s), -128.f), 127.f);
        u.c[v4*4+3] = (char)(int)fminf(fmaxf(rintf(f.w / s), -128.f), 127.f);
    }
    qx[idx] = u.v;
}

// ---------------- quantize w: per-row (out-channel) scale ----------------
__global__ __launch_bounds__(256) void quant_w_kernel(
    const float* __restrict__ w, const float* __restrict__ w_scale,
    i32x4* __restrict__ qw, int n16)
{
    int idx = blockIdx.x * 256 + threadIdx.x;
    if (idx >= n16) return;
    float s = w_scale[idx >> 7];   // K=2048 -> 128 threads (of 16 elems) per row
    const float4* wp = reinterpret_cast<const float4*>(w) + (size_t)idx * 4;
    union { char c[16]; i32x4 v; } u;
#pragma unroll
    for (int v4 = 0; v4 < 4; ++v4) {
        float4 f = wp[v4];
        u.c[v4*4+0] = (char)(int)fminf(fmaxf(rintf(f.x / s), -128.f), 127.f);
        u.c[v4*4+1] = (char)(int)fminf(fmaxf(rintf(f.y / s), -128.f), 127.f);
        u.c[v4*4+2] = (char)(int)fminf(fmaxf(rintf(f.z / s), -128.f), 127.f);
        u.c[v4*4+3] = (char)(int)fminf(fmaxf(rintf(f.w / s), -128.f), 127.f);
    }
    qw[idx] = u.v;
}

// ---------------- per-out-channel combined scale + dequantized bias ----------------
__global__ __launch_bounds__(256) void prep_kernel(
    const float* __restrict__ bias, const float* __restrict__ in_scale,
    const float* __restrict__ w_scale, const float* __restrict__ b_scale,
    float* __restrict__ oscale, float* __restrict__ obias, int n)
{
    int i = blockIdx.x * 256 + threadIdx.x;
    if (i >= n) return;
    oscale[i] = in_scale[0] * w_scale[i] * 0.5f;   // W_ALPHA
    float bs = b_scale[i];
    float q = fminf(fmaxf(rintf(bias[i] / bs), -128.f), 127.f);
    obias[i] = q * bs * 0.75f;                      // B_BETA
}

// ---------------- int8 GEMM: 128x128 tile; A in LDS, B global->reg; 3 blocks/CU ----------
// R11 post-mortem: LDS pipe 4x oversubscribed vs MFMA (88KB/block-tile vs 163cy of
// MFMA). Fix: take B off the LDS pipe. 4 waves (2Mx2N), per-wave 64x64 (acc=64).
// A: LDS 2-deep (8KB/tile, 16 KiB total), R2-verified swizzle -> 0 conflicts.
// B: global->reg, wave = 16 consecutive rows x 64B = full cache lines, 2-tile
// prefetch depth (3 rotating reg sets), counted vmcnt(4) gates (never 0 mid-loop).
// R8's failure (latency exposure) fixed by: 2-deep prefetch + counted gates +
// 3 independent blocks/CU (launch_bounds(256,3)) + XCD COLUMN-STRIPE swizzle so
// each XCD's B working set = 8 panels = 2MB (L2-resident; R8's swizzle thrashed
// 16MB). LDS/block-tile = 24KB (188cy) < MFMA (327cy) -> MFMA-bound by design.
// vmcnt ledger (tile t): enter with B(t+1) 4 outstanding; issue A(t+1) 2 + B(t+2) 4
// -> 10; gate vmcnt(4) retires B(t+1)+A(t+1), leaves B(t+2). Barrier certifies A(t+1).
__global__ __launch_bounds__(256, 3) void gemm_i8_kernel(
    const char* __restrict__ qx,   // [M][K] int8
    const char* __restrict__ qw,   // [N][K] int8
    const float* __restrict__ oscale,
    const float* __restrict__ obias,
    float* __restrict__ out)       // [M][N] fp32
{
    __shared__ __align__(16) char ldsA[2 * 8192];

    const int t    = threadIdx.x;          // 0..255
    const int lane = t & 63;
    const int wid  = t >> 6;               // 0..3
    const int wm   = wid >> 1;             // 0..1
    const int wn   = wid & 1;              // 0..1

    // XCD column-stripe swizzle: xcd = bid&7 owns col-blocks [xcd*8, xcd*8+8),
    // iterating cols-fastest so the 8 sharers of an A panel are adjacent in dispatch.
    int bid = blockIdx.x;                   // 4096 blocks
    int sl  = bid >> 3;                     // 0..511 within XCD
    const size_t brow = (size_t)(sl >> 3) * 128;                    // 64 row-blocks
    const size_t bcol = (size_t)((bid & 7) * 8 + (sl & 7)) * 128;   // 64 col-blocks

    // A staging: 2 calls x (256 threads x 16B) cover 128 rows x 64B. Thread t:
    // row c*64 + t/4, 16B slot t&3 (linear dest). Global source pre-swizzled:
    // logical slot = (t&3) ^ ((row>>1)&3) = (t&3) ^ ((t>>3)&3)  [invariant under +64].
    const int srow  = t >> 2;              // 0..63
    const int lslot = (t & 3) ^ ((t >> 3) & 3);
    const char* gA = qx + (brow + srow) * K_DIM + lslot * 16;
    char* dstA = ldsA + t * 16;

#define STAGE_A(tt_) do {                                                                 \
    __builtin_amdgcn_global_load_lds((const AS1 unsigned int*)(gA + (tt_) * 64),          \
        (AS3 unsigned int*)(dstA + ((tt_) & 1) * 8192), 16, 0, 0);                        \
    __builtin_amdgcn_global_load_lds((const AS1 unsigned int*)(gA + (tt_) * 64 + 64 * K_DIM), \
        (AS3 unsigned int*)(dstA + ((tt_) & 1) * 8192 + 4096), 16, 0, 0);                 \
  } while (0)

    // A frag read offsets (swizzled): row rA, slot kg ^ ((rA>>1)&3); frag m = +m*1024
    // (swizzle-invariant: +16 rows = +8 in r>>1 = 0 mod 4).
    const int lrow = lane & 15;
    const int kg   = lane >> 4;            // 16B k-group 0..3
    const int rA   = wm * 64 + lrow;
    const int offA0 = rA * 64 + ((kg ^ ((rA >> 1) & 3)) * 16);

    // B global base: lane reads 16B at row (bcol + wn*64 + nt*16 + lrow), k-byte kg*16.
    const char* gBf = qw + (bcol + (size_t)wn * 64 + lrow) * K_DIM + kg * 16;

#define LOADB(tt_, B0_, B1_, B2_, B3_) do {                                               \
    const char* p_ = gBf + (tt_) * 64;                                                    \
    B0_ = *(const i32x4*)(p_);                                                            \
    B1_ = *(const i32x4*)(p_ + 16 * K_DIM);                                               \
    B2_ = *(const i32x4*)(p_ + 32 * K_DIM);                                               \
    B3_ = *(const i32x4*)(p_ + 48 * K_DIM);                                               \
  } while (0)

    i32x4 acc[4][4];
#pragma unroll
    for (int m = 0; m < 4; ++m)
#pragma unroll
        for (int n = 0; n < 4; ++n)
            acc[m][n] = (i32x4){0, 0, 0, 0};

#define MM(m_, n_, a_, b_) acc[m_][n_] = __builtin_amdgcn_mfma_i32_16x16x64_i8((a_), (b_), acc[m_][n_], 0, 0, 0)
#define BAR() do { __builtin_amdgcn_s_barrier(); asm volatile("" ::: "memory"); } while (0)
#define VMC4() asm volatile("s_waitcnt vmcnt(4)" ::: "memory")
#define VMC0() asm volatile("s_waitcnt vmcnt(0)" ::: "memory")

    // KT: GATE_ 0 = vmcnt(4)+BAR (steady), 1 = vmcnt(0)+BAR (t=30), 2 = none (t=31).
#define KT(tt_, BC0,BC1,BC2,BC3, BL0,BL1,BL2,BL3, PFA_, PFB_, GATE_) do {                 \
    const char* bAp = ldsA + ((tt_) & 1) * 8192;                                          \
    if (PFA_) STAGE_A((tt_) + 1);                                                         \
    if (PFB_) LOADB((tt_) + 2, BL0, BL1, BL2, BL3);                                       \
    i32x4 a0 = *(const i32x4*)(bAp + offA0);                                              \
    i32x4 a1 = *(const i32x4*)(bAp + offA0 + 1024);                                       \
    i32x4 a2 = *(const i32x4*)(bAp + offA0 + 2048);                                       \
    i32x4 a3 = *(const i32x4*)(bAp + offA0 + 3072);                                       \
    __builtin_amdgcn_s_setprio(1);                                                        \
    MM(0,0,a0,BC0); MM(0,1,a0,BC1); MM(0,2,a0,BC2); MM(0,3,a0,BC3);                       \
    MM(1,0,a1,BC0); MM(1,1,a1,BC1); MM(1,2,a1,BC2); MM(1,3,a1,BC3);                       \
    MM(2,0,a2,BC0); MM(2,1,a2,BC1); MM(2,2,a2,BC2); MM(2,3,a2,BC3);                       \
    MM(3,0,a3,BC0); MM(3,1,a3,BC1); MM(3,2,a3,BC2); MM(3,3,a3,BC3);                       \
    __builtin_amdgcn_s_setprio(0);                                                        \
    if ((GATE_) == 0)      { VMC4(); BAR(); }                                             \
    else if ((GATE_) == 1) { VMC0(); BAR(); }                                             \
  } while (0)

    // prologue: A(0) staged; B(0)->BX, B(1)->BY issued. vmcnt(4) retires A(0)+B(0),
    // leaves B(1) in flight (matches steady-state entry condition). Barrier certifies A(0).
    i32x4 BX0, BX1, BX2, BX3, BY0, BY1, BY2, BY3, BZ0, BZ1, BZ2, BZ3;
    STAGE_A(0);
    LOADB(0, BX0, BX1, BX2, BX3);
    LOADB(1, BY0, BY1, BY2, BY3);
    VMC4();
    BAR();

    // tiles 0..29, 3-way B-reg rotation (tile t: cur = b[t%3], load B(t+2) -> b[(t+2)%3])
    for (int it = 0; it < 10; ++it) {
        KT(3*it,     BX0,BX1,BX2,BX3, BZ0,BZ1,BZ2,BZ3, 1, 1, 0);
        KT(3*it + 1, BY0,BY1,BY2,BY3, BX0,BX1,BX2,BX3, 1, 1, 0);
        KT(3*it + 2, BZ0,BZ1,BZ2,BZ3, BY0,BY1,BY2,BY3, 1, 1, 0);
    }
    // tail: tile 30 (cur BX; stage A(31); drain all: B(31) + A(31)); tile 31 (cur BY)
    KT(30, BX0,BX1,BX2,BX3, BZ0,BZ1,BZ2,BZ3, 1, 0, 1);
    KT(31, BY0,BY1,BY2,BY3, BZ0,BZ1,BZ2,BZ3, 0, 0, 2);

#undef KT
#undef LOADB
#undef STAGE_A
#undef MM
#undef BAR
#undef VMC4
#undef VMC0

    // epilogue: C/D layout col = lane&15, row = (lane>>4)*4 + j
    const int colq = lane & 15;
    const int rowq = lane >> 4;
#pragma unroll
    for (int n = 0; n < 4; ++n) {
        size_t col = bcol + wn * 64 + n * 16 + colq;
        float sc = oscale[col];
        float bi = obias[col];
#pragma unroll
        for (int m = 0; m < 4; ++m) {
            size_t rbase = brow + wm * 64 + m * 16 + (size_t)rowq * 4;
#pragma unroll
            for (int j = 0; j < 4; ++j)
                out[(rbase + j) * N_DIM + col] = (float)acc[m][n][j] * sc + bi;
        }
    }
}

extern "C" void kernel_launch(void* const* d_in, const int* in_sizes, int n_in,
                              void* d_out, int out_size, void* d_ws, size_t ws_size,
                              hipStream_t stream) {
    const float* x        = (const float*)d_in[0];
    const float* weight   = (const float*)d_in[1];
    const float* bias     = (const float*)d_in[2];
    const float* in_scale = (const float*)d_in[3];
    const float* w_scale  = (const float*)d_in[4];
    const float* b_scale  = (const float*)d_in[5];
    float* out = (float*)d_out;

    char* ws = (char*)d_ws;
    const size_t xk = (size_t)M_DIM * K_DIM;
    const size_t wk = (size_t)N_DIM * K_DIM;
    char*  qx     = ws;
    char*  qw     = ws + xk;
    float* oscale = (float*)(ws + xk + wk);
    float* obias  = oscale + N_DIM;

    const int n16 = (int)(xk / 16);   // 1,048,576 = 4096 * 256
    quant_x_kernel<<<4096, 256, 0, stream>>>(x, in_scale, (i32x4*)qx, n16);
    quant_w_kernel<<<4096, 256, 0, stream>>>(weight, w_scale, (i32x4*)qw, n16);
    prep_kernel<<<32, 256, 0, stream>>>(bias, in_scale, w_scale, b_scale, oscale, obias, N_DIM);

    gemm_i8_kernel<<<4096, 256, 0, stream>>>(qx, qw, oscale, obias, out);
}

// Round 13
// 236.862 us; speedup vs baseline: 1.3382x; 1.3382x over previous
//
#include <hip/hip_runtime.h>

typedef int i32x4 __attribute__((ext_vector_type(4)));

#define AS1 __attribute__((address_space(1)))
#define AS3 __attribute__((address_space(3)))

#define M_DIM 8192
#define N_DIM 8192
#define K_DIM 2048
#define NT 32   // K-tiles of 64 bytes

// ---------------- quantize x: per-tensor scale, 16 elems/thread ----------------
__global__ __launch_bounds__(256) void quant_x_kernel(
    const float* __restrict__ x, const float* __restrict__ in_scale,
    i32x4* __restrict__ qx, int n16)
{
    int idx = blockIdx.x * 256 + threadIdx.x;
    if (idx >= n16) return;
    float s = in_scale[0];
    const float4* xp = reinterpret_cast<const float4*>(x) + (size_t)idx * 4;
    union { char c[16]; i32x4 v; } u;
#pragma unroll
    for (int v4 = 0; v4 < 4; ++v4) {
        float4 f = xp[v4];
        u.c[v4*4+0] = (char)(int)fminf(fmaxf(rintf(f.x / s), -128.f), 127.f);
        u.c[v4*4+1] = (char)(int)fminf(fmaxf(rintf(f.y / s), -128.f), 127.f);
        u.c[v4*4+2] = (char)(int)fminf(fmaxf(rintf(f.z / s), -128.f), 127.f);
        u.c[v4*4+3] = (char)(int)fminf(fmaxf(rintf(f.w / s), -128.f), 127.f);
    }
    qx[idx] = u.v;
}

// ---------------- quantize w: per-row (out-channel) scale ----------------
__global__ __launch_bounds__(256) void quant_w_kernel(
    const float* __restrict__ w, const float* __restrict__ w_scale,
    i32x4* __restrict__ qw, int n16)
{
    int idx = blockIdx.x * 256 + threadIdx.x;
    if (idx >= n16) return;
    float s = w_scale[idx >> 7];   // K=2048 -> 128 threads (of 16 elems) per row
    const float4* wp = reinterpret_cast<const float4*>(w) + (size_t)idx * 4;
    union { char c[16]; i32x4 v; } u;
#pragma unroll
    for (int v4 = 0; v4 < 4; ++v4) {
        float4 f = wp[v4];
        u.c[v4*4+0] = (char)(int)fminf(fmaxf(rintf(f.x / s), -128.f), 127.f);
        u.c[v4*4+1] = (char)(int)fminf(fmaxf(rintf(f.y / s), -128.f), 127.f);
        u.c[v4*4+2] = (char)(int)fminf(fmaxf(rintf(f.z / s), -128.f), 127.f);
        u.c[v4*4+3] = (char)(int)fminf(fmaxf(rintf(f.w / s), -128.f), 127.f);
    }
    qw[idx] = u.v;
}

// ---------------- per-out-channel combined scale + dequantized bias ----------------
__global__ __launch_bounds__(256) void prep_kernel(
    const float* __restrict__ bias, const float* __restrict__ in_scale,
    const float* __restrict__ w_scale, const float* __restrict__ b_scale,
    float* __restrict__ oscale, float* __restrict__ obias, int n)
{
    int i = blockIdx.x * 256 + threadIdx.x;
    if (i >= n) return;
    oscale[i] = in_scale[0] * w_scale[i] * 0.5f;   // W_ALPHA
    float bs = b_scale[i];
    float q = fminf(fmaxf(rintf(bias[i] / bs), -128.f), 127.f);
    obias[i] = q * bs * 0.75f;                      // B_BETA
}

// ---------------- int8 GEMM: 256x128 tile, 4 waves of 128x64, 2 blocks/CU ----------------
// R11 improvement: per-wave tile 64x64 -> 128x64 cuts ds_read bytes per output 1.5x
// (block-K-tile LDS = 72KB vs 88KB for same 32K outputs). MFMA becomes the binding
// per-CU resource (pair 1306cy vs LDS ~1100cy). Keeps R11's win ingredient: TWO
// INDEPENDENT blocks/CU (each SIMD holds 2 waves from different blocks; one block's
// MFMA covers the other's stage/vmcnt/barrier stalls — m114). acc = 8x4 frags = 128
// regs; total ~190 <= 256 at launch_bounds(256,2); LDS 48KiB x 2 = 96 <= 160.
// Swizzle (R2/R11-verified, 0 conflicts): 16B-slot' = slot ^ ((row>>1)&3),
// inverse-swizzled GLOBAL source + linear global_load_lds dest (rule 21).
// Schedule = R11's proven loop: {stage(t+1); 12 ds_read; 32 MFMA; vmcnt(0); bar}.
// Ring safety: at tile t's opening barrier all waves' reads of buf (t+1)&1 are done.
__global__ __launch_bounds__(256, 2) void gemm_i8_kernel(
    const char* __restrict__ qx,   // [M][K] int8
    const char* __restrict__ qw,   // [N][K] int8
    const float* __restrict__ oscale,
    const float* __restrict__ obias,
    float* __restrict__ out)       // [M][N] fp32
{
    __shared__ __align__(16) char ldsA[2 * 16384];
    __shared__ __align__(16) char ldsB[2 * 8192];

    const int t    = threadIdx.x;          // 0..255
    const int lane = t & 63;
    const int wid  = t >> 6;               // 0..3
    const int wm   = wid >> 1;             // 0..1 -> rows [wm*128, wm*128+128)
    const int wn   = wid & 1;              // 0..1 -> cols [wn*64, wn*64+64)

    // XCD-aware swizzle: 2048 blocks, 2048 % 8 == 0 -> bijective
    int bid = blockIdx.x;
    int sid = (bid & 7) * 256 + (bid >> 3);
    const size_t brow = (size_t)(sid >> 6) * 256;   // 32 M-tiles
    const size_t bcol = (size_t)(sid & 63) * 128;   // 64 N-tiles

    // staging: per call 256 threads cover 64 rows x 64 B (4KB). Thread t: row
    // c*64 + t/4, 16B slot t&3 (linear dest). Global source pre-swizzled:
    // logical slot = (t&3) ^ ((row>>1)&3) = (t&3) ^ ((t>>3)&3)  [invariant under +64].
    const int srow  = t >> 2;              // 0..63
    const int lslot = (t & 3) ^ ((t >> 3) & 3);
    const char* gA = qx + (brow + srow) * K_DIM + lslot * 16;
    const char* gB = qw + (bcol + srow) * K_DIM + lslot * 16;
    char* dstA = ldsA + t * 16;
    char* dstB = ldsB + t * 16;

#define STAGE(tt_) do {                                                                   \
    const int bb_ = (tt_) & 1; const int ko_ = (tt_) * 64;                                \
    __builtin_amdgcn_global_load_lds((const AS1 unsigned int*)(gA + ko_),                 \
        (AS3 unsigned int*)(dstA + bb_ * 16384), 16, 0, 0);                               \
    __builtin_amdgcn_global_load_lds((const AS1 unsigned int*)(gA + ko_ + 64 * K_DIM),    \
        (AS3 unsigned int*)(dstA + bb_ * 16384 + 4096), 16, 0, 0);                        \
    __builtin_amdgcn_global_load_lds((const AS1 unsigned int*)(gA + ko_ + 128 * K_DIM),   \
        (AS3 unsigned int*)(dstA + bb_ * 16384 + 8192), 16, 0, 0);                        \
    __builtin_amdgcn_global_load_lds((const AS1 unsigned int*)(gA + ko_ + 192 * K_DIM),   \
        (AS3 unsigned int*)(dstA + bb_ * 16384 + 12288), 16, 0, 0);                       \
    __builtin_amdgcn_global_load_lds((const AS1 unsigned int*)(gB + ko_),                 \
        (AS3 unsigned int*)(dstB + bb_ * 8192), 16, 0, 0);                                \
    __builtin_amdgcn_global_load_lds((const AS1 unsigned int*)(gB + ko_ + 64 * K_DIM),    \
        (AS3 unsigned int*)(dstB + bb_ * 8192 + 4096), 16, 0, 0);                         \
  } while (0)

    // frag read offsets (swizzled): row r, slot kg ^ ((r>>1)&3); frag step = 16 rows
    // = +1024 B (swizzle-invariant: +8 in r>>1 == 0 mod 4).
    const int lrow = lane & 15;
    const int kg   = lane >> 4;            // 16B k-group 0..3
    const int rA   = wm * 128 + lrow;
    const int rB   = wn * 64 + lrow;
    const int offA0 = rA * 64 + ((kg ^ ((rA >> 1) & 3)) * 16);
    const int offB0 = rB * 64 + ((kg ^ ((rB >> 1) & 3)) * 16);

    i32x4 acc[8][4];
#pragma unroll
    for (int m = 0; m < 8; ++m)
#pragma unroll
        for (int n = 0; n < 4; ++n)
            acc[m][n] = (i32x4){0, 0, 0, 0};

#define MM(m_, n_, a_, b_) acc[m_][n_] = __builtin_amdgcn_mfma_i32_16x16x64_i8((a_), (b_), acc[m_][n_], 0, 0, 0)
#define BAR() do { __builtin_amdgcn_s_barrier(); asm volatile("" ::: "memory"); } while (0)
#define VMCNT0() asm volatile("s_waitcnt vmcnt(0)" ::: "memory")

    // prologue: tile 0 staged and certified
    STAGE(0);
    VMCNT0();
    BAR();

    for (int tt = 0; tt < NT; ++tt) {
        const char* bA = ldsA + (tt & 1) * 16384;
        const char* bB = ldsB + (tt & 1) * 8192;
        const bool pf = (tt + 1) < NT;

        if (pf) STAGE(tt + 1);

        i32x4 a0 = *(const i32x4*)(bA + offA0);
        i32x4 a1 = *(const i32x4*)(bA + offA0 + 1024);
        i32x4 a2 = *(const i32x4*)(bA + offA0 + 2048);
        i32x4 a3 = *(const i32x4*)(bA + offA0 + 3072);
        i32x4 a4 = *(const i32x4*)(bA + offA0 + 4096);
        i32x4 a5 = *(const i32x4*)(bA + offA0 + 5120);
        i32x4 a6 = *(const i32x4*)(bA + offA0 + 6144);
        i32x4 a7 = *(const i32x4*)(bA + offA0 + 7168);
        i32x4 b0 = *(const i32x4*)(bB + offB0);
        i32x4 b1 = *(const i32x4*)(bB + offB0 + 1024);
        i32x4 b2 = *(const i32x4*)(bB + offB0 + 2048);
        i32x4 b3 = *(const i32x4*)(bB + offB0 + 3072);

        __builtin_amdgcn_s_setprio(1);
        MM(0,0,a0,b0); MM(0,1,a0,b1); MM(0,2,a0,b2); MM(0,3,a0,b3);
        MM(1,0,a1,b0); MM(1,1,a1,b1); MM(1,2,a1,b2); MM(1,3,a1,b3);
        MM(2,0,a2,b0); MM(2,1,a2,b1); MM(2,2,a2,b2); MM(2,3,a2,b3);
        MM(3,0,a3,b0); MM(3,1,a3,b1); MM(3,2,a3,b2); MM(3,3,a3,b3);
        MM(4,0,a4,b0); MM(4,1,a4,b1); MM(4,2,a4,b2); MM(4,3,a4,b3);
        MM(5,0,a5,b0); MM(5,1,a5,b1); MM(5,2,a5,b2); MM(5,3,a5,b3);
        MM(6,0,a6,b0); MM(6,1,a6,b1); MM(6,2,a6,b2); MM(6,3,a6,b3);
        MM(7,0,a7,b0); MM(7,1,a7,b1); MM(7,2,a7,b2); MM(7,3,a7,b3);
        __builtin_amdgcn_s_setprio(0);

        if (pf) {
            VMCNT0();   // drain covered by this tile's 12 reads + 32 MFMA + other block
            BAR();      // certifies tile tt+1; reads of tt done -> stage(tt+2) safe
        }
    }
#undef STAGE
#undef MM
#undef BAR
#undef VMCNT0

    // epilogue: C/D layout col = lane&15, row = (lane>>4)*4 + j
    const int colq = lane & 15;
    const int rowq = lane >> 4;
#pragma unroll
    for (int n = 0; n < 4; ++n) {
        size_t col = bcol + wn * 64 + n * 16 + colq;
        float sc = oscale[col];
        float bi = obias[col];
#pragma unroll
        for (int m = 0; m < 8; ++m) {
            size_t rbase = brow + wm * 128 + m * 16 + (size_t)rowq * 4;
#pragma unroll
            for (int j = 0; j < 4; ++j)
                out[(rbase + j) * N_DIM + col] = (float)acc[m][n][j] * sc + bi;
        }
    }
}

extern "C" void kernel_launch(void* const* d_in, const int* in_sizes, int n_in,
                              void* d_out, int out_size, void* d_ws, size_t ws_size,
                              hipStream_t stream) {
    const float* x        = (const float*)d_in[0];
    const float* weight   = (const float*)d_in[1];
    const float* bias     = (const float*)d_in[2];
    const float* in_scale = (const float*)d_in[3];
    const float* w_scale  = (const float*)d_in[4];
    const float* b_scale  = (const float*)d_in[5];
    float* out = (float*)d_out;

    char* ws = (char*)d_ws;
    const size_t xk = (size_t)M_DIM * K_DIM;
    const size_t wk = (size_t)N_DIM * K_DIM;
    char*  qx     = ws;
    char*  qw     = ws + xk;
    float* oscale = (float*)(ws + xk + wk);
    float* obias  = oscale + N_DIM;

    const int n16 = (int)(xk / 16);   // 1,048,576 = 4096 * 256
    quant_x_kernel<<<4096, 256, 0, stream>>>(x, in_scale, (i32x4*)qx, n16);
    quant_w_kernel<<<4096, 256, 0, stream>>>(weight, w_scale, (i32x4*)qw, n16);
    prep_kernel<<<32, 256, 0, stream>>>(bias, in_scale, w_scale, b_scale, oscale, obias, N_DIM);

    gemm_i8_kernel<<<2048, 256, 0, stream>>>(qx, qw, oscale, obias, out);
}